// Round 4
// baseline (146.671 us; speedup 1.0000x reference)
//
#include <hip/hip_runtime.h>
#include <hip/hip_bf16.h>
#include <stdint.h>

typedef short s16x8 __attribute__((ext_vector_type(8)));
typedef float f32x4 __attribute__((ext_vector_type(4)));

static constexpr int DDIM = 256;
static constexpr float TEN_LOG2E = 14.4269504088896340736f; // 10 * log2(e)

// ---------------- Kernel 1: row-normalize p = [z_i; z_j], cast to bf16 ----------------
// Also zero-inits row_s[8192] (blocks 0..7) and out[0] (block 0).
__global__ __launch_bounds__(256) void normalize_bf16_kernel(
    const float* __restrict__ zi, const float* __restrict__ zj,
    ushort* __restrict__ pn, float* __restrict__ row_s, float* __restrict__ out)
{
    if (blockIdx.x < 8) {
        ((float4*)row_s)[blockIdx.x * 256 + threadIdx.x] = (float4){0.f, 0.f, 0.f, 0.f};
        if (blockIdx.x == 0 && threadIdx.x == 0) out[0] = 0.0f;
    }

    const int row  = blockIdx.x * 4 + (threadIdx.x >> 6);
    const int lane = threadIdx.x & 63;
    const float* src = (row < 4096) ? (zi + (size_t)row * DDIM)
                                    : (zj + (size_t)(row - 4096) * DDIM);
    float4 v = ((const float4*)src)[lane];
    float ss = v.x * v.x + v.y * v.y + v.z * v.z + v.w * v.w;
    #pragma unroll
    for (int off = 32; off > 0; off >>= 1) ss += __shfl_xor(ss, off, 64);
    const float inv = 1.0f / fmaxf(sqrtf(ss), 1e-8f);

    ushort4 o;
    o.x = __builtin_bit_cast(unsigned short, __float2bfloat16(v.x * inv));
    o.y = __builtin_bit_cast(unsigned short, __float2bfloat16(v.y * inv));
    o.z = __builtin_bit_cast(unsigned short, __float2bfloat16(v.z * inv));
    o.w = __builtin_bit_cast(unsigned short, __float2bfloat16(v.w * inv));
    ((ushort4*)(pn + (size_t)row * DDIM))[lane] = o;
}

// ---------------- Kernel 2: upper-triangle Gram tiles, fragments direct from cache ----
// 2080 blocks = 64*65/2 upper-triangle 128x128 tiles, 4 waves each computing a 64x64
// sub-tile with 16x16x32 MFMA (4x4 frags). NO LDS, NO barriers: A/B fragments are
// loaded straight from global (pn is 4MB, L2-resident). For 16x16x32, lane(l15,q)
// reads pn[row=l15][k0 + q*8 .. +8] = 16B; the 4 quads of 16 lanes cover one full
// 64B line per row -> perfectly line-efficient scattered loads.
__global__ __launch_bounds__(256, 3) void simexp_kernel(
    const ushort* __restrict__ pn,
    float* __restrict__ row_s,
    float* __restrict__ pos_out)
{
    const int tid  = threadIdx.x;
    const int w    = tid >> 6;
    const int lane = tid & 63;
    const int q    = lane >> 4;      // 0..3: K-octet of the MFMA operand
    const int l15  = lane & 15;
    const int wm   = (w >> 1) * 64;  // wave row offset in 128x128 tile
    const int wn   = (w & 1) * 64;   // wave col offset

    // ---- upper-triangle decode: block b -> (ti, tj), ti <= tj ----
    const int b = blockIdx.x;
    int ti = (int)(64.5f - sqrtf(64.5f * 64.5f - 2.0f * (float)b));
    while ((ti + 1) * 64 - ((ti + 1) * ti) / 2 <= b) ++ti;
    while (ti * 64 - (ti * (ti - 1)) / 2 > b) --ti;
    const int tj = ti + (b - (ti * 64 - (ti * (ti - 1)) / 2));
    const int r0 = ti * 128, c0 = tj * 128;
    const bool diag  = (ti == tj);
    const bool ptile = (tj == ti + 32);  // contains positive-pair diagonal

    // per-lane fragment base pointers (16B at +kt*64B per K-step)
    const ushort* pa[4];
    const ushort* pb[4];
    #pragma unroll
    for (int mi = 0; mi < 4; ++mi)
        pa[mi] = pn + (size_t)(r0 + wm + mi * 16 + l15) * DDIM + q * 8;
    #pragma unroll
    for (int ni = 0; ni < 4; ++ni)
        pb[ni] = pn + (size_t)(c0 + wn + ni * 16 + l15) * DDIM + q * 8;

    f32x4 acc[4][4];
    #pragma unroll
    for (int mi = 0; mi < 4; ++mi)
        #pragma unroll
        for (int ni = 0; ni < 4; ++ni)
            acc[mi][ni] = (f32x4){0.f, 0.f, 0.f, 0.f};

    #pragma unroll
    for (int kt = 0; kt < 8; ++kt) {
        s16x8 af[4], bfr[4];
        #pragma unroll
        for (int mi = 0; mi < 4; ++mi)
            af[mi] = *(const s16x8*)(pa[mi] + kt * 32);
        #pragma unroll
        for (int ni = 0; ni < 4; ++ni)
            bfr[ni] = *(const s16x8*)(pb[ni] + kt * 32);

        #pragma unroll
        for (int mi = 0; mi < 4; ++mi)
            #pragma unroll
            for (int ni = 0; ni < 4; ++ni)
                acc[mi][ni] = __builtin_amdgcn_mfma_f32_16x16x32_bf16(
                    af[mi], bfr[ni], acc[mi][ni], 0, 0, 0);
    }

    // ---- epilogue: exp, diag mask, positive extraction, row+col sums ----
    // C/D layout (16x16): col = lane&15, row = q*4 + r
    float rsum[4][4];
    float csum[4] = {0.f, 0.f, 0.f, 0.f};
    #pragma unroll
    for (int mi = 0; mi < 4; ++mi)
        #pragma unroll
        for (int r = 0; r < 4; ++r) rsum[mi][r] = 0.0f;

    #pragma unroll
    for (int mi = 0; mi < 4; ++mi)
        #pragma unroll
        for (int ni = 0; ni < 4; ++ni)
            #pragma unroll
            for (int r = 0; r < 4; ++r) {
                const int lr = wm + mi * 16 + q * 4 + r;
                const int lc = wn + ni * 16 + l15;
                float e = exp2f(acc[mi][ni][r] * TEN_LOG2E);
                if (diag && lr == lc) e = 0.0f;          // mask self-similarity
                rsum[mi][r] += e;
                csum[ni]    += e;
                if (ptile && lr == lc) {                 // positive pair: col = row + 4096
                    const float v = acc[mi][ni][r] * 10.0f;
                    pos_out[r0 + lr] = v;
                    pos_out[c0 + lr] = v;
                }
            }

    // row sums: reduce across the 16 lanes (cols) of each quad
    #pragma unroll
    for (int mi = 0; mi < 4; ++mi)
        #pragma unroll
        for (int r = 0; r < 4; ++r) {
            float v = rsum[mi][r];
            v += __shfl_xor(v, 1, 64);
            v += __shfl_xor(v, 2, 64);
            v += __shfl_xor(v, 4, 64);
            v += __shfl_xor(v, 8, 64);
            rsum[mi][r] = v;
        }
    if (l15 == 0) {
        #pragma unroll
        for (int mi = 0; mi < 4; ++mi)
            #pragma unroll
            for (int r = 0; r < 4; ++r)
                atomicAdd(&row_s[r0 + wm + mi * 16 + q * 4 + r], rsum[mi][r]);
    }

    // col sums (symmetric contribution): reduce across quads (rows), skip on diagonal
    if (!diag) {
        #pragma unroll
        for (int ni = 0; ni < 4; ++ni) {
            float v = csum[ni];
            v += __shfl_xor(v, 16, 64);
            v += __shfl_xor(v, 32, 64);
            if (q == 0)
                atomicAdd(&row_s[c0 + wn + ni * 16 + l15], v);
        }
    }
}

// ---------------- Kernel 3: finalize loss ----------------
__global__ __launch_bounds__(256) void finalize_kernel(
    const float* __restrict__ row_s, const float* __restrict__ pos,
    float* __restrict__ out)
{
    const int i = blockIdx.x * 256 + threadIdx.x;   // float4 index, 2048 total
    float4 s = ((const float4*)row_s)[i];
    float4 p = ((const float4*)pos)[i];
    float local = (__logf(s.x) - p.x) + (__logf(s.y) - p.y)
                + (__logf(s.z) - p.z) + (__logf(s.w) - p.w);
    #pragma unroll
    for (int off = 32; off > 0; off >>= 1) local += __shfl_xor(local, off, 64);
    __shared__ float red[4];
    if ((threadIdx.x & 63) == 0) red[threadIdx.x >> 6] = local;
    __syncthreads();
    if (threadIdx.x == 0)
        atomicAdd(out, (red[0] + red[1] + red[2] + red[3]) * (1.0f / 8192.0f));
}

// ---------------- Launch ----------------
extern "C" void kernel_launch(void* const* d_in, const int* in_sizes, int n_in,
                              void* d_out, int out_size, void* d_ws, size_t ws_size,
                              hipStream_t stream)
{
    const float* zi = (const float*)d_in[0];
    const float* zj = (const float*)d_in[1];

    ushort* pn   = (ushort*)d_ws;                                    // 4 MB bf16 normalized rows
    float* row_s = (float*)((char*)d_ws + (4u << 20));               // 8192 fp32
    float* pos   = (float*)((char*)d_ws + (4u << 20) + (32u << 10)); // 8192 fp32
    float* out   = (float*)d_out;

    hipLaunchKernelGGL(normalize_bf16_kernel, dim3(2048), dim3(256), 0, stream,
                       zi, zj, pn, row_s, out);
    hipLaunchKernelGGL(simexp_kernel, dim3(2080), dim3(256), 0, stream, pn, row_s, pos);
    hipLaunchKernelGGL(finalize_kernel, dim3(8), dim3(256), 0, stream, row_s, pos, out);
}